// Round 5
// baseline (626.190 us; speedup 1.0000x reference)
//
#include <hip/hip_runtime.h>

// B=16, T=64, HW=7 (HW2=49), D=768, N=12, C=64, 3D=2304
// x:(B,T,7,7,768) fp32; out:(B,T,768) fp32
// R8: qkv GEMM simplified to 2-barriers-per-K-tile (counted vmcnt dbuf,
// compiler-interleaved ds_read/MFMA, 2 blocks/CU). Rest unchanged from R7.

typedef __attribute__((ext_vector_type(8))) short bf16x8;
typedef __attribute__((ext_vector_type(4))) float f32x4;

#define AS1U(p) ((const __attribute__((address_space(1))) unsigned int*)(p))
#define AS3U(p) ((__attribute__((address_space(3))) unsigned int*)(p))

__device__ __forceinline__ unsigned short cvt_bf16(float x) {
  union { float f; unsigned int u; } v; v.f = x;
  unsigned int r = v.u + 0x7fffu + ((v.u >> 16) & 1u);
  return (unsigned short)(r >> 16);
}
__device__ __forceinline__ float bf2f(unsigned short h) {
  union { unsigned int u; float f; } v; v.u = ((unsigned int)h) << 16;
  return v.f;
}

__device__ __forceinline__ void wg_barrier() {
  asm volatile("" ::: "memory");
  __builtin_amdgcn_s_barrier();
  asm volatile("" ::: "memory");
}

// ---------------------------------------------------------------------------
// fp32 -> bf16 (8 elems/thread)
// ---------------------------------------------------------------------------
__global__ __launch_bounds__(256) void cvt_x_k(const float* __restrict__ src,
                                               unsigned short* __restrict__ dst, int n8) {
  int i = blockIdx.x * 256 + threadIdx.x;
  if (i >= n8) return;
  const float4* s = (const float4*)src + (size_t)i * 2;
  float4 a = s[0], b = s[1];
  ushort4 r0 = { cvt_bf16(a.x), cvt_bf16(a.y), cvt_bf16(a.z), cvt_bf16(a.w) };
  ushort4 r1 = { cvt_bf16(b.x), cvt_bf16(b.y), cvt_bf16(b.z), cvt_bf16(b.w) };
  ushort4* d = (ushort4*)dst + (size_t)i * 2;
  d[0] = r0; d[1] = r1;
}

// ---------------------------------------------------------------------------
// Wqkv [768][2304] fp32 -> WqkvT [2304][768] bf16
// ---------------------------------------------------------------------------
__global__ __launch_bounds__(256) void transpose_cvt_k(const float* __restrict__ src,
                                                       unsigned short* __restrict__ dst) {
  __shared__ float tl[32][33];
  int k0 = blockIdx.x * 32, n0 = blockIdx.y * 32;
  int tx = threadIdx.x & 31, ty = threadIdx.x >> 5;
#pragma unroll
  for (int r = 0; r < 32; r += 8)
    tl[ty + r][tx] = src[(size_t)(k0 + ty + r) * 2304 + n0 + tx];
  __syncthreads();
#pragma unroll
  for (int r = 0; r < 32; r += 8)
    dst[(size_t)(n0 + ty + r) * 768 + k0 + tx] = cvt_bf16(tl[tx][ty + r]);
}

// ---------------------------------------------------------------------------
// Fused prep: Wp{q,k,v} [d*3136 + c*49 + hw] fp32 -> WpTT [(p,hw,d,c)] bf16
// (blocks 0..2399), relp (127,64)->(128,64) bf16 (blocks 2400..2431).
// ---------------------------------------------------------------------------
__global__ __launch_bounds__(256) void prep_cvt_k(
    const float* __restrict__ Wpq, const float* __restrict__ Wpk,
    const float* __restrict__ Wpv, const float* __restrict__ relp,
    unsigned short* __restrict__ WpTT, unsigned short* __restrict__ relb) {
  int bid = blockIdx.x;
  if (bid < 2400) {
    int p = bid / 800;
    const float* src = (p == 0) ? Wpq : (p == 1) ? Wpk : Wpv;
    unsigned short* dst = WpTT + (size_t)p * 204800;
    int o = (bid - p * 800) * 256 + threadIdx.x;
    if (o >= 204800) return;
    int c = o & 63, d = (o >> 6) & 63, hw = o >> 12;
    dst[o] = (hw < 49) ? cvt_bf16(src[d * 3136 + c * 49 + hw]) : (unsigned short)0;
  } else {
    int i = (bid - 2400) * 256 + threadIdx.x;   // 8192
    relb[i] = (i < 8128) ? cvt_bf16(relp[i]) : (unsigned short)0;
  }
}

// ---------------------------------------------------------------------------
// qkv GEMM: C[m][n] = sum_k A[m][k]*Bt[n][k], M=50176, N=2304, K=768, bf16 out.
// R8: BM=BN=128, BK=64, 256 thr (4 waves 2x2), 64 KB LDS dbuf, 2 blocks/CU.
// 2 barriers per K-tile: {vmcnt(8); bar; 16 ds_read + 32 MFMA (compiler-
// interleaved via lgkmcnt); bar; restage}. T2 swizzle, XCD swizzle kept.
// ---------------------------------------------------------------------------
__global__ __launch_bounds__(256, 2) void gemm_qkv_128(
    const unsigned short* __restrict__ A, const unsigned short* __restrict__ Bt,
    unsigned short* __restrict__ Cb) {
  __shared__ unsigned short As[2][8192];   // [buf][128*64]
  __shared__ unsigned short Bs[2][8192];

  // XCD swizzle: 7056 blocks = 882 * 8 (exactly divisible)
  const int orig = blockIdx.x;
  const int xcd = orig & 7;
  const int slot = orig >> 3;               // 0..881
  const int mb = xcd * 49 + slot / 18;      // 0..391, m-contiguous per XCD
  const int nb = slot % 18;                 // n fastest -> A-panel L2-hot
  const int m0 = mb * 128, n0 = nb * 128;
  const int K = 768;

  const int tid = threadIdx.x;
  const int wave = tid >> 6, lane = tid & 63;
  const int quad = lane >> 4, l16 = lane & 15;
  const int wr = wave >> 1, wc = wave & 1;  // 2 x 2 wave grid
  const int x7 = l16 & 7;

  // staging: thread t, batch l: row = l*32 + (t>>3), pre-swizzled chunk
  const int srow = tid >> 3;                // 0..31
  const int cs = (tid & 7) ^ (srow & 7);
  const unsigned short* Ag[4];
  const unsigned short* Bg[4];
#pragma unroll
  for (int l = 0; l < 4; ++l) {
    Ag[l] = A + (size_t)(m0 + l * 32 + srow) * K + cs * 8;
    Bg[l] = Bt + (size_t)(n0 + l * 32 + srow) * K + cs * 8;
  }
  const int ldst = wave * 512;              // wave-uniform LDS dest (elements)

#define STAGE_A(buf, kt) do {                                                      \
    const int ko_ = (kt) * 64;                                                     \
    _Pragma("unroll")                                                              \
    for (int l_ = 0; l_ < 4; ++l_)                                                 \
      __builtin_amdgcn_global_load_lds(AS1U(Ag[l_] + ko_),                         \
          AS3U(&As[buf][l_ * 2048 + ldst]), 16, 0, 0);                             \
  } while (0)

#define STAGE_B(buf, kt) do {                                                      \
    const int ko_ = (kt) * 64;                                                     \
    _Pragma("unroll")                                                              \
    for (int l_ = 0; l_ < 4; ++l_)                                                 \
      __builtin_amdgcn_global_load_lds(AS1U(Bg[l_] + ko_),                         \
          AS3U(&Bs[buf][l_ * 2048 + ldst]), 16, 0, 0);                             \
  } while (0)

#define LDA(dst, buf, mi) do {                                                     \
    _Pragma("unroll")                                                              \
    for (int fi_ = 0; fi_ < 2; ++fi_) {                                            \
      const int row_ = wr * 64 + (mi) * 32 + fi_ * 16 + l16;                       \
      _Pragma("unroll")                                                            \
      for (int ks_ = 0; ks_ < 2; ++ks_)                                            \
        dst[fi_][ks_] = *(const bf16x8*)&As[buf][row_ * 64 +                       \
            (((ks_ * 4 + quad) ^ x7) * 8)];                                        \
    }                                                                              \
  } while (0)

#define LDB(dst, buf, nj) do {                                                     \
    _Pragma("unroll")                                                              \
    for (int fj_ = 0; fj_ < 2; ++fj_) {                                            \
      const int row_ = wc * 64 + (nj) * 32 + fj_ * 16 + l16;                       \
      _Pragma("unroll")                                                            \
      for (int ks_ = 0; ks_ < 2; ++ks_)                                            \
        dst[fj_][ks_] = *(const bf16x8*)&Bs[buf][row_ * 64 +                       \
            (((ks_ * 4 + quad) ^ x7) * 8)];                                        \
    }                                                                              \
  } while (0)

#define MFMAQ(a_, b_, mi, nj) do {                                                 \
    _Pragma("unroll")                                                              \
    for (int ks_ = 0; ks_ < 2; ++ks_)                                              \
      _Pragma("unroll")                                                            \
      for (int fi_ = 0; fi_ < 2; ++fi_)                                            \
        _Pragma("unroll")                                                          \
        for (int fj_ = 0; fj_ < 2; ++fj_)                                          \
          acc[(mi) * 2 + fi_][(nj) * 2 + fj_] =                                    \
              __builtin_amdgcn_mfma_f32_16x16x32_bf16(a_[fi_][ks_],                \
                  b_[fj_][ks_], acc[(mi) * 2 + fi_][(nj) * 2 + fj_], 0, 0, 0);     \
  } while (0)

// one K-tile: data-ready wait -> all loads + all MFMAs -> read-done -> restage
#define ITER(cur, DO_STAGE, kt2, VMI) do {                                         \
    asm volatile("s_waitcnt vmcnt(" #VMI ")" ::: "memory");                        \
    wg_barrier();                                                                  \
    LDA(af0, cur, 0); LDB(bf0, cur, 0); LDB(bf1, cur, 1); LDA(af1, cur, 1);        \
    __builtin_amdgcn_s_setprio(1);                                                 \
    MFMAQ(af0, bf0, 0, 0); MFMAQ(af0, bf1, 0, 1);                                  \
    MFMAQ(af1, bf0, 1, 0); MFMAQ(af1, bf1, 1, 1);                                  \
    __builtin_amdgcn_s_setprio(0);                                                 \
    wg_barrier();                                                                  \
    if (DO_STAGE) { STAGE_B(cur, kt2); STAGE_A(cur, kt2); }                        \
  } while (0)

  f32x4 acc[4][4];
#pragma unroll
  for (int i = 0; i < 4; ++i)
#pragma unroll
    for (int j = 0; j < 4; ++j) acc[i][j] = (f32x4){0.f, 0.f, 0.f, 0.f};
  bf16x8 af0[2][2], af1[2][2], bf0[2][2], bf1[2][2];

  // prologue: 2 K-tiles in flight (8 loads per tile)
  STAGE_B(0, 0); STAGE_A(0, 0);
  STAGE_B(1, 1); STAGE_A(1, 1);

  // main loop: 12 K-tiles, stage kt+2, counted vmcnt(8)
  for (int kt = 0; kt < 10; kt += 2) {
    ITER(0, true, kt + 2, 8);
    ITER(1, true, kt + 3, 8);
  }
  ITER(0, false, 0, 8);   // kt=10: tile 11 still in flight
  ITER(1, false, 0, 0);   // kt=11: final drain

#undef ITER
#undef MFMAQ
#undef LDB
#undef LDA
#undef STAGE_B
#undef STAGE_A

  // epilogue: C write (bf16), wave tile 64x64 at (wr*64, wc*64)
#pragma unroll
  for (int i = 0; i < 4; ++i)
#pragma unroll
    for (int j = 0; j < 4; ++j)
#pragma unroll
      for (int r = 0; r < 4; ++r) {
        int row = m0 + wr * 64 + i * 16 + quad * 4 + r;
        int col = n0 + wc * 64 + j * 16 + l16;
        Cb[(size_t)row * 2304 + col] = cvt_bf16(acc[i][j][r]);
      }
}

// ---------------------------------------------------------------------------
// Pool + bias + LayerNorm, MFMA, BK=128 (2 hw per iter, 25 iters).
// Double-buffered staging with counted vmcnt(8) — R6-verified.
// ---------------------------------------------------------------------------
__global__ __launch_bounds__(256) void pool_ln_mfma_k(
    const unsigned short* __restrict__ qkvb, const unsigned short* __restrict__ WpTT,
    const float* __restrict__ bq, const float* __restrict__ bk, const float* __restrict__ bv,
    const float* __restrict__ gq, const float* __restrict__ gk, const float* __restrict__ gv,
    const float* __restrict__ beq, const float* __restrict__ bek, const float* __restrict__ bev,
    unsigned short* __restrict__ oq, unsigned short* __restrict__ ok_,
    unsigned short* __restrict__ ov) {
  __shared__ float smem_f[16384];          // 64 KB: A0,A1,B0,B1 bf16 / Ln alias
  __shared__ float mu_s[64], rs_s[64];
  unsigned short* AB = (unsigned short*)smem_f;  // A(buf)=AB+buf*8192; B=+16384
  float* Ln = smem_f;                      // [64][65], valid after K-loop

  const int n = blockIdx.x, p = blockIdx.y, b = blockIdx.z;
  const int tid = threadIdx.x;
  const int wave = tid >> 6, lane = tid & 63;
  const int quad = lane >> 4, l16 = lane & 15;
  const int wm = (wave >> 1) * 32, wn = (wave & 1) * 32;

  const int lr = lane >> 4, lg = lane & 15;
  const size_t abase = ((size_t)b * 3136) * 2304 + (size_t)p * 768 + (size_t)n * 64;
  const unsigned short* WpB = WpTT + (size_t)p * 204800;

  const unsigned short* pA[4];
  const unsigned short* pB[4];
#pragma unroll
  for (int q = 0; q < 4; ++q) {
    int r = wave * 16 + q * 4 + lr;
    int g = lg ^ (r & 15);
    pA[q] = qkvb + abase + (size_t)r * 112896 + (size_t)(g >> 3) * 2304 + (g & 7) * 8;
    pB[q] = WpB + (size_t)(g >> 3) * 4096 + r * 64 + (g & 7) * 8;
  }

#define PSTAGE(buf, it) do {                                                       \
    const size_t offA_ = (size_t)(it) * 4608;                                      \
    const size_t offB_ = (size_t)(it) * 8192;                                      \
    unsigned short* Ad_ = AB + (buf) * 8192;                                       \
    unsigned short* Bd_ = AB + 16384 + (buf) * 8192;                               \
    _Pragma("unroll")                                                              \
    for (int q_ = 0; q_ < 4; ++q_) {                                               \
      __builtin_amdgcn_global_load_lds(AS1U(pA[q_] + offA_),                       \
          AS3U(&Ad_[(wave * 16 + q_ * 4) * 128]), 16, 0, 0);                       \
      __builtin_amdgcn_global_load_lds(AS1U(pB[q_] + offB_),                       \
          AS3U(&Bd_[(wave * 16 + q_ * 4) * 128]), 16, 0, 0);                       \
    }                                                                              \
  } while (0)

#define PCOMPUTE(buf) do {                                                         \
    const unsigned short* Ad_ = AB + (buf) * 8192;                                 \
    const unsigned short* Bd_ = AB + 16384 + (buf) * 8192;                         \
    bf16x8 af_[2][4], bf_[2][4];                                                   \
    _Pragma("unroll")                                                              \
    for (int f_ = 0; f_ < 2; ++f_) {                                               \
      int ra_ = wm + f_ * 16 + l16;                                                \
      int rb_ = wn + f_ * 16 + l16;                                                \
      _Pragma("unroll")                                                            \
      for (int ki_ = 0; ki_ < 4; ++ki_) {                                          \
        af_[f_][ki_] = *(const bf16x8*)&Ad_[ra_ * 128 +                            \
            (((ki_ * 4 + quad) ^ (ra_ & 15)) * 8)];                                \
        bf_[f_][ki_] = *(const bf16x8*)&Bd_[rb_ * 128 +                            \
            (((ki_ * 4 + quad) ^ (rb_ & 15)) * 8)];                                \
      }                                                                            \
    }                                                                              \
    _Pragma("unroll")                                                              \
    for (int ki_ = 0; ki_ < 4; ++ki_)                                              \
      _Pragma("unroll")                                                            \
      for (int i_ = 0; i_ < 2; ++i_)                                               \
        _Pragma("unroll")                                                          \
        for (int j_ = 0; j_ < 2; ++j_)                                             \
          acc[i_][j_] = __builtin_amdgcn_mfma_f32_16x16x32_bf16(                   \
              af_[i_][ki_], bf_[j_][ki_], acc[i_][j_], 0, 0, 0);                   \
  } while (0)

  f32x4 acc[2][2];
#pragma unroll
  for (int i = 0; i < 2; ++i)
#pragma unroll
    for (int j = 0; j < 2; ++j) acc[i][j] = (f32x4){0.f, 0.f, 0.f, 0.f};

  PSTAGE(0, 0);
  for (int it2 = 0; it2 < 24; it2 += 2) {
    PSTAGE(1, it2 + 1);
    asm volatile("s_waitcnt vmcnt(8)" ::: "memory");
    wg_barrier();
    PCOMPUTE(0);
    wg_barrier();
    PSTAGE(0, it2 + 2);
    asm volatile("s_waitcnt vmcnt(8)" ::: "memory");
    wg_barrier();
    PCOMPUTE(1);
    wg_barrier();
  }
  // it = 24 (buf 0), last tile -> full drain
  asm volatile("s_waitcnt vmcnt(0)" ::: "memory");
  wg_barrier();
  PCOMPUTE(0);
  __syncthreads();                         // all reads done before Ln aliases AB

#undef PCOMPUTE
#undef PSTAGE

  const float* bias = (p == 0) ? bq : (p == 1) ? bk : bv;
  const float* g    = (p == 0) ? gq : (p == 1) ? gk : gv;
  const float* be   = (p == 0) ? beq : (p == 1) ? bek : bev;
  unsigned short* outp = (p == 0) ? oq : (p == 1) ? ok_ : ov;

#pragma unroll
  for (int i = 0; i < 2; ++i)
#pragma unroll
    for (int j = 0; j < 2; ++j)
#pragma unroll
      for (int r = 0; r < 4; ++r) {
        int t = wm + i * 16 + quad * 4 + r;
        int d = wn + j * 16 + l16;
        Ln[t * 65 + d] = acc[i][j][r] + bias[d];
      }
  __syncthreads();
  if (tid < 64) {
    float s = 0.f;
#pragma unroll 8
    for (int c = 0; c < 64; ++c) s += Ln[tid * 65 + c];
    float m = s * (1.f / 64.f);
    float v2 = 0.f;
#pragma unroll 8
    for (int c = 0; c < 64; ++c) { float dl = Ln[tid * 65 + c] - m; v2 += dl * dl; }
    mu_s[tid] = m;
    rs_s[tid] = rsqrtf(v2 * (1.f / 64.f) + 1e-5f);
  }
  __syncthreads();
  {
    int t = tid >> 2, d0 = (tid & 3) * 16;
    float m = mu_s[t], rv = rs_s[t];
    unsigned short ob[16];
#pragma unroll
    for (int j = 0; j < 16; ++j)
      ob[j] = cvt_bf16((Ln[t * 65 + d0 + j] - m) * rv * g[d0 + j] + be[d0 + j]);
    unsigned short* dst = outp + ((size_t)(b * 12 + n) * 64 + t) * 64 + d0;
    *(uint4*)dst = *(uint4*)ob;
    *(uint4*)(dst + 8) = *(uint4*)(ob + 8);
  }
}

// ---------------------------------------------------------------------------
// Fused MFMA attention per (b,n) — R3-verified verbatim.
// ---------------------------------------------------------------------------
__global__ __launch_bounds__(256) void attn_mfma_k(
    const unsigned short* __restrict__ qp, const unsigned short* __restrict__ kp,
    const unsigned short* __restrict__ vp, const unsigned short* __restrict__ relb,
    float* __restrict__ aout) {
  __shared__ unsigned short qs[64 * 64];
  __shared__ unsigned short ks[64 * 64];
  __shared__ unsigned short vt[64 * 64];
  __shared__ unsigned short rs[128 * 64];
  __shared__ float Gs[64 * 128];
  __shared__ unsigned short Ps[64 * 64];

  const int n = blockIdx.x, b = blockIdx.y;
  const int tid = threadIdx.x;
  const size_t base = ((size_t)b * 12 + n) * 4096;

  for (int i = tid; i < 512; i += 256) {
    ((uint4*)qs)[i] = ((const uint4*)(qp + base))[i];
    ((uint4*)ks)[i] = ((const uint4*)(kp + base))[i];
  }
  for (int i = tid; i < 1024; i += 256)
    ((uint4*)rs)[i] = ((const uint4*)relb)[i];
  {
    int s = tid >> 2, c0 = (tid & 3) * 16;
    unsigned short tmp[16];
    *(uint4*)tmp = *(const uint4*)(vp + base + s * 64 + c0);
    *(uint4*)(tmp + 8) = *(const uint4*)(vp + base + s * 64 + c0 + 8);
#pragma unroll
    for (int i = 0; i < 16; ++i) vt[(c0 + i) * 64 + s] = tmp[i];
  }
  __syncthreads();

  const int wave = tid >> 6, lane = tid & 63;
  const int quad = lane >> 4, l16 = lane & 15;
  const int tm = wave * 16;

  bf16x8 aq[2];
  aq[0] = *(const bf16x8*)&qs[(tm + l16) * 64 + quad * 8];
  aq[1] = *(const bf16x8*)&qs[(tm + l16) * 64 + quad * 8 + 32];

  f32x4 accqk[4], accg[8];
#pragma unroll
  for (int j = 0; j < 4; ++j) accqk[j] = (f32x4){0.f, 0.f, 0.f, 0.f};
#pragma unroll
  for (int j = 0; j < 8; ++j) accg[j] = (f32x4){0.f, 0.f, 0.f, 0.f};

#pragma unroll
  for (int ki = 0; ki < 2; ++ki) {
#pragma unroll
    for (int j = 0; j < 4; ++j) {
      bf16x8 bk = *(const bf16x8*)&ks[(j * 16 + l16) * 64 + quad * 8 + ki * 32];
      accqk[j] = __builtin_amdgcn_mfma_f32_16x16x32_bf16(aq[ki], bk, accqk[j], 0, 0, 0);
    }
#pragma unroll
    for (int j = 0; j < 8; ++j) {
      bf16x8 br = *(const bf16x8*)&rs[(j * 16 + l16) * 64 + quad * 8 + ki * 32];
      accg[j] = __builtin_amdgcn_mfma_f32_16x16x32_bf16(aq[ki], br, accg[j], 0, 0, 0);
    }
  }
#pragma unroll
  for (int j = 0; j < 8; ++j)
#pragma unroll
    for (int r = 0; r < 4; ++r)
      Gs[(tm + quad * 4 + r) * 128 + j * 16 + l16] = accg[j][r];
  __syncthreads();

#pragma unroll
  for (int r = 0; r < 4; ++r) {
    int t = tm + quad * 4 + r;
    float sv[4];
#pragma unroll
    for (int j = 0; j < 4; ++j) {
      int s = j * 16 + l16;
      sv[j] = 0.125f * accqk[j][r] + Gs[t * 128 + (t + 63 - s)];
    }
    float m = fmaxf(fmaxf(sv[0], sv[1]), fmaxf(sv[2], sv[3]));
    m = fmaxf(m, __shfl_xor(m, 1));
    m = fmaxf(m, __shfl_xor(m, 2));
    m = fmaxf(m, __shfl_xor(m, 4));
    m = fmaxf(m, __shfl_xor(m, 8));
    float e[4], sum = 0.f;
#pragma unroll
    for (int j = 0; j < 4; ++j) { e[j] = __expf(sv[j] - m); sum += e[j]; }
    sum += __shfl_xor(sum, 1);
    sum += __shfl_xor(sum, 2);
    sum += __shfl_xor(sum, 4);
    sum += __shfl_xor(sum, 8);
    float inv = 1.f / sum;
#pragma unroll
    for (int j = 0; j < 4; ++j)
      Ps[t * 64 + j * 16 + l16] = cvt_bf16(e[j] * inv);
  }
  __syncthreads();

  bf16x8 ap[2];
  ap[0] = *(const bf16x8*)&Ps[(tm + l16) * 64 + quad * 8];
  ap[1] = *(const bf16x8*)&Ps[(tm + l16) * 64 + quad * 8 + 32];
  f32x4 acco[4];
#pragma unroll
  for (int j = 0; j < 4; ++j) acco[j] = (f32x4){0.f, 0.f, 0.f, 0.f};
#pragma unroll
  for (int ki = 0; ki < 2; ++ki)
#pragma unroll
    for (int j = 0; j < 4; ++j) {
      bf16x8 bv = *(const bf16x8*)&vt[(j * 16 + l16) * 64 + quad * 8 + ki * 32];
      acco[j] = __builtin_amdgcn_mfma_f32_16x16x32_bf16(ap[ki], bv, acco[j], 0, 0, 0);
    }
#pragma unroll
  for (int j = 0; j < 4; ++j)
#pragma unroll
    for (int r = 0; r < 4; ++r) {
      int t = tm + quad * 4 + r;
      int c = j * 16 + l16;
      float o = acco[j][r] + bf2f(qs[t * 64 + c]);
      aout[((size_t)b * 64 + t) * 768 + n * 64 + c] = o;
    }
}

// ---------------------------------------------------------------------------
// fp32 GEMM (final projection): C[m,n] = sum_k A[m,k]*B[k,n] + bias[n]
// ---------------------------------------------------------------------------
__global__ __launch_bounds__(256) void gemm_f32_k(
    const float* __restrict__ A, const float* __restrict__ Bm,
    const float* __restrict__ bias, float* __restrict__ Cm,
    int M, int Nn, int K) {
  __shared__ float As[16][68];
  __shared__ float Bs[16][64];
  const int tid = threadIdx.x;
  const int ty = tid >> 4, tx = tid & 15;
  const int m0 = blockIdx.y * 64, n0 = blockIdx.x * 64;

  const int la_m = tid >> 2;
  const int la_k = (tid & 3) << 2;
  const int lb_k = tid >> 4;
  const int lb_n = (tid & 15) << 2;

  const float* Ap = A + (size_t)(m0 + la_m) * K + la_k;
  const float* Bp = Bm + (size_t)lb_k * Nn + n0 + lb_n;

  float acc[4][4];
#pragma unroll
  for (int i = 0; i < 4; ++i)
#pragma unroll
    for (int j = 0; j < 4; ++j) acc[i][j] = 0.f;

  for (int k0 = 0; k0 < K; k0 += 16) {
    float4 av = *(const float4*)(Ap + k0);
    float4 bv = *(const float4*)(Bp + (size_t)k0 * Nn);
    As[la_k + 0][la_m] = av.x;
    As[la_k + 1][la_m] = av.y;
    As[la_k + 2][la_m] = av.z;
    As[la_k + 3][la_m] = av.w;
    *(float4*)&Bs[lb_k][lb_n] = bv;
    __syncthreads();
#pragma unroll
    for (int kk = 0; kk < 16; ++kk) {
      float af[4], bf[4];
      *(float4*)af = *(const float4*)&As[kk][ty << 2];
      *(float4*)bf = *(const float4*)&Bs[kk][tx << 2];
#pragma unroll
      for (int i = 0; i < 4; ++i)
#pragma unroll
        for (int j = 0; j < 4; ++j) acc[i][j] += af[i] * bf[j];
    }
    __syncthreads();
  }

  float bb[4] = {0.f, 0.f, 0.f, 0.f};
  if (bias) {
#pragma unroll
    for (int j = 0; j < 4; ++j) bb[j] = bias[n0 + (tx << 2) + j];
  }
#pragma unroll
  for (int i = 0; i < 4; ++i) {
    float4 o;
    o.x = acc[i][0] + bb[0];
    o.y = acc[i][1] + bb[1];
    o.z = acc[i][2] + bb[2];
    o.w = acc[i][3] + bb[3];
    *(float4*)(Cm + (size_t)(m0 + (ty << 2) + i) * Nn + n0 + (tx << 2)) = o;
  }
}

// ---------------------------------------------------------------------------
extern "C" void kernel_launch(void* const* d_in, const int* in_sizes, int n_in,
                              void* d_out, int out_size, void* d_ws, size_t ws_size,
                              hipStream_t stream) {
  const float* x     = (const float*)d_in[0];
  const float* Wqkv  = (const float*)d_in[1];
  const float* Wpq   = (const float*)d_in[2];
  const float* bpq   = (const float*)d_in[3];
  const float* Wpk   = (const float*)d_in[4];
  const float* bpk   = (const float*)d_in[5];
  const float* Wpv   = (const float*)d_in[6];
  const float* bpv   = (const float*)d_in[7];
  const float* gq    = (const float*)d_in[8];
  const float* beq   = (const float*)d_in[9];
  const float* gk    = (const float*)d_in[10];
  const float* bek   = (const float*)d_in[11];
  const float* gv    = (const float*)d_in[12];
  const float* bev   = (const float*)d_in[13];
  const float* relp  = (const float*)d_in[14];
  const float* Wproj = (const float*)d_in[15];
  const float* bproj = (const float*)d_in[16];
  float* out = (float*)d_out;

  unsigned short* u = (unsigned short*)d_ws;
  unsigned short* xbf   = u;                       // 38,535,168 us
  unsigned short* qkvbf = u + 38535168ull;         // 115,605,504 us
  unsigned short* WqkvT = u + 154140672ull;        // 1,769,472 us
  unsigned short* WpTT  = u + 155910144ull;        // 614,400 us
  unsigned short* relb  = u + 156524544ull;        // 8,192 us
  unsigned short* qpb   = u + 156532736ull;        // 786,432 us
  unsigned short* kpb   = u + 157319168ull;        // 786,432 us
  unsigned short* vpb   = u + 158105600ull;        // 786,432 us
  float* aout = (float*)(u + 158892032ull);        // 786,432 f32

  cvt_x_k<<<18816, 256, 0, stream>>>(x, xbf, 4816896);
  transpose_cvt_k<<<dim3(24, 72), 256, 0, stream>>>(Wqkv, WqkvT);
  prep_cvt_k<<<2432, 256, 0, stream>>>(Wpq, Wpk, Wpv, relp, WpTT, relb);

  // qkv = x @ Wqkv (bf16 MFMA, 128x128 2-barrier dbuf, 2 blocks/CU)
  gemm_qkv_128<<<7056, 256, 0, stream>>>(xbf, WqkvT, qkvbf);

  // pooling + bias + LN (bf16 MFMA, double-buffered)
  pool_ln_mfma_k<<<dim3(12, 3, 16), 256, 0, stream>>>(
      qkvbf, WpTT, bpq, bpk, bpv, gq, gk, gv, beq, bek, bev, qpb, kpb, vpb);

  // attention (MFMA)
  attn_mfma_k<<<dim3(12, 16), 256, 0, stream>>>(qpb, kpb, vpb, relb, aout);

  // final projection (fp32)
  gemm_f32_k<<<dim3(12, 16), 256, 0, stream>>>(aout, Wproj, bproj, out, 1024, 768, 768);
}

// Round 6
// 594.278 us; speedup vs baseline: 1.0537x; 1.0537x over previous
//
#include <hip/hip_runtime.h>

// B=16, T=64, HW=7 (HW2=49), D=768, N=12, C=64, 3D=2304
// x:(B,T,7,7,768) fp32; out:(B,T,768) fp32
// R9: gemm reverted to R7-verified 4-phase body, split into 2 launches
// (nb-halves) so second-tier kernels become visible in top-5 profiling.

typedef __attribute__((ext_vector_type(8))) short bf16x8;
typedef __attribute__((ext_vector_type(4))) float f32x4;

#define AS1U(p) ((const __attribute__((address_space(1))) unsigned int*)(p))
#define AS3U(p) ((__attribute__((address_space(3))) unsigned int*)(p))

__device__ __forceinline__ unsigned short cvt_bf16(float x) {
  union { float f; unsigned int u; } v; v.f = x;
  unsigned int r = v.u + 0x7fffu + ((v.u >> 16) & 1u);
  return (unsigned short)(r >> 16);
}
__device__ __forceinline__ float bf2f(unsigned short h) {
  union { unsigned int u; float f; } v; v.u = ((unsigned int)h) << 16;
  return v.f;
}

__device__ __forceinline__ void wg_barrier() {
  asm volatile("" ::: "memory");
  __builtin_amdgcn_s_barrier();
  asm volatile("" ::: "memory");
}

// ---------------------------------------------------------------------------
// fp32 -> bf16 (8 elems/thread)
// ---------------------------------------------------------------------------
__global__ __launch_bounds__(256) void cvt_x_k(const float* __restrict__ src,
                                               unsigned short* __restrict__ dst, int n8) {
  int i = blockIdx.x * 256 + threadIdx.x;
  if (i >= n8) return;
  const float4* s = (const float4*)src + (size_t)i * 2;
  float4 a = s[0], b = s[1];
  ushort4 r0 = { cvt_bf16(a.x), cvt_bf16(a.y), cvt_bf16(a.z), cvt_bf16(a.w) };
  ushort4 r1 = { cvt_bf16(b.x), cvt_bf16(b.y), cvt_bf16(b.z), cvt_bf16(b.w) };
  ushort4* d = (ushort4*)dst + (size_t)i * 2;
  d[0] = r0; d[1] = r1;
}

// ---------------------------------------------------------------------------
// Wqkv [768][2304] fp32 -> WqkvT [2304][768] bf16
// ---------------------------------------------------------------------------
__global__ __launch_bounds__(256) void transpose_cvt_k(const float* __restrict__ src,
                                                       unsigned short* __restrict__ dst) {
  __shared__ float tl[32][33];
  int k0 = blockIdx.x * 32, n0 = blockIdx.y * 32;
  int tx = threadIdx.x & 31, ty = threadIdx.x >> 5;
#pragma unroll
  for (int r = 0; r < 32; r += 8)
    tl[ty + r][tx] = src[(size_t)(k0 + ty + r) * 2304 + n0 + tx];
  __syncthreads();
#pragma unroll
  for (int r = 0; r < 32; r += 8)
    dst[(size_t)(n0 + ty + r) * 768 + k0 + tx] = cvt_bf16(tl[tx][ty + r]);
}

// ---------------------------------------------------------------------------
// Fused prep: Wp{q,k,v} -> WpTT bf16 (blocks 0..2399), relp -> relb
// ---------------------------------------------------------------------------
__global__ __launch_bounds__(256) void prep_cvt_k(
    const float* __restrict__ Wpq, const float* __restrict__ Wpk,
    const float* __restrict__ Wpv, const float* __restrict__ relp,
    unsigned short* __restrict__ WpTT, unsigned short* __restrict__ relb) {
  int bid = blockIdx.x;
  if (bid < 2400) {
    int p = bid / 800;
    const float* src = (p == 0) ? Wpq : (p == 1) ? Wpk : Wpv;
    unsigned short* dst = WpTT + (size_t)p * 204800;
    int o = (bid - p * 800) * 256 + threadIdx.x;
    if (o >= 204800) return;
    int c = o & 63, d = (o >> 6) & 63, hw = o >> 12;
    dst[o] = (hw < 49) ? cvt_bf16(src[d * 3136 + c * 49 + hw]) : (unsigned short)0;
  } else {
    int i = (bid - 2400) * 256 + threadIdx.x;   // 8192
    relb[i] = (i < 8128) ? cvt_bf16(relp[i]) : (unsigned short)0;
  }
}

// ---------------------------------------------------------------------------
// qkv GEMM: C[m][n] = sum_k A[m][k]*Bt[n][k], M=50176, N=2304, K=768, bf16 out.
// R7-verified 4-phase body. Launched twice over nb-halves (nb_off 0 / 9);
// per launch grid 3528 = 441 slots x 8 XCDs (441 = 49 mb x 9 nb).
// ---------------------------------------------------------------------------
__global__ __launch_bounds__(256, 2) void gemm_qkv_128(
    const unsigned short* __restrict__ A, const unsigned short* __restrict__ Bt,
    unsigned short* __restrict__ Cb, int nb_off) {
  __shared__ unsigned short As[2][8192];   // [buf][128*64]
  __shared__ unsigned short Bs[2][8192];

  const int orig = blockIdx.x;
  const int xcd = orig & 7;
  const int slot = orig >> 3;               // 0..440
  const int mb = xcd * 49 + slot / 9;       // 0..391, m-contiguous per XCD
  const int nb = slot % 9 + nb_off;         // n fastest -> A-panel L2-hot
  const int m0 = mb * 128, n0 = nb * 128;
  const int K = 768;

  const int tid = threadIdx.x;
  const int wave = tid >> 6, lane = tid & 63;
  const int quad = lane >> 4, l16 = lane & 15;
  const int wr = wave >> 1, wc = wave & 1;  // 2 x 2 wave grid
  const int x7 = l16 & 7;

  // staging: thread t, batch l: row = l*32 + (t>>3), pre-swizzled chunk
  const int srow = tid >> 3;                // 0..31
  const int cs = (tid & 7) ^ (srow & 7);
  const unsigned short* Ag[4];
  const unsigned short* Bg[4];
#pragma unroll
  for (int l = 0; l < 4; ++l) {
    Ag[l] = A + (size_t)(m0 + l * 32 + srow) * K + cs * 8;
    Bg[l] = Bt + (size_t)(n0 + l * 32 + srow) * K + cs * 8;
  }
  const int ldst = wave * 512;              // wave-uniform LDS dest (elements)

#define STAGE_A(buf, kt) do {                                                      \
    const int ko_ = (kt) * 64;                                                     \
    _Pragma("unroll")                                                              \
    for (int l_ = 0; l_ < 4; ++l_)                                                 \
      __builtin_amdgcn_global_load_lds(AS1U(Ag[l_] + ko_),                         \
          AS3U(&As[buf][l_ * 2048 + ldst]), 16, 0, 0);                             \
  } while (0)

#define STAGE_B(buf, kt) do {                                                      \
    const int ko_ = (kt) * 64;                                                     \
    _Pragma("unroll")                                                              \
    for (int l_ = 0; l_ < 4; ++l_)                                                 \
      __builtin_amdgcn_global_load_lds(AS1U(Bg[l_] + ko_),                         \
          AS3U(&Bs[buf][l_ * 2048 + ldst]), 16, 0, 0);                             \
  } while (0)

#define LDA(dst, buf, mi) do {                                                     \
    _Pragma("unroll")                                                              \
    for (int fi_ = 0; fi_ < 2; ++fi_) {                                            \
      const int row_ = wr * 64 + (mi) * 32 + fi_ * 16 + l16;                       \
      _Pragma("unroll")                                                            \
      for (int ks_ = 0; ks_ < 2; ++ks_)                                            \
        dst[fi_][ks_] = *(const bf16x8*)&As[buf][row_ * 64 +                       \
            (((ks_ * 4 + quad) ^ x7) * 8)];                                        \
    }                                                                              \
  } while (0)

#define LDB(dst, buf, nj) do {                                                     \
    _Pragma("unroll")                                                              \
    for (int fj_ = 0; fj_ < 2; ++fj_) {                                            \
      const int row_ = wc * 64 + (nj) * 32 + fj_ * 16 + l16;                       \
      _Pragma("unroll")                                                            \
      for (int ks_ = 0; ks_ < 2; ++ks_)                                            \
        dst[fj_][ks_] = *(const bf16x8*)&Bs[buf][row_ * 64 +                       \
            (((ks_ * 4 + quad) ^ x7) * 8)];                                        \
    }                                                                              \
  } while (0)

#define MFMAQ(a_, b_, mi, nj) do {                                                 \
    _Pragma("unroll")                                                              \
    for (int ks_ = 0; ks_ < 2; ++ks_)                                              \
      _Pragma("unroll")                                                            \
      for (int fi_ = 0; fi_ < 2; ++fi_)                                            \
        _Pragma("unroll")                                                          \
        for (int fj_ = 0; fj_ < 2; ++fj_)                                          \
          acc[(mi) * 2 + fi_][(nj) * 2 + fj_] =                                    \
              __builtin_amdgcn_mfma_f32_16x16x32_bf16(a_[fi_][ks_],                \
                  b_[fj_][ks_], acc[(mi) * 2 + fi_][(nj) * 2 + fj_], 0, 0, 0);     \
  } while (0)

#define ITER(cur, DO_STAGE, kt2, VMI) do {                                         \
    asm volatile("s_waitcnt vmcnt(" #VMI ")" ::: "memory");                        \
    wg_barrier();                                                                  \
    /* P1: quadrant (0,0) */                                                       \
    LDA(af0, cur, 0); LDB(bf0, cur, 0);                                            \
    wg_barrier();                                                                  \
    __builtin_amdgcn_s_setprio(1); MFMAQ(af0, bf0, 0, 0);                          \
    __builtin_amdgcn_s_setprio(0);                                                 \
    wg_barrier();                                                                  \
    /* P2: quadrant (0,1) */                                                       \
    LDB(bf1, cur, 1);                                                              \
    wg_barrier();                                                                  \
    __builtin_amdgcn_s_setprio(1); MFMAQ(af0, bf1, 0, 1);                          \
    __builtin_amdgcn_s_setprio(0);                                                 \
    wg_barrier();                                                                  \
    /* P3: quadrant (1,0); B-buf fully read after P2 -> safe to restage B */       \
    LDA(af1, cur, 1);                                                              \
    if (DO_STAGE) STAGE_B(cur, kt2);                                               \
    wg_barrier();                                                                  \
    __builtin_amdgcn_s_setprio(1); MFMAQ(af1, bf0, 1, 0);                          \
    __builtin_amdgcn_s_setprio(0);                                                 \
    wg_barrier();                                                                  \
    /* P4: quadrant (1,1); A-buf fully read after P3 -> safe to restage A */       \
    if (DO_STAGE) STAGE_A(cur, kt2);                                               \
    __builtin_amdgcn_s_setprio(1); MFMAQ(af1, bf1, 1, 1);                          \
    __builtin_amdgcn_s_setprio(0);                                                 \
    wg_barrier();                                                                  \
  } while (0)

  f32x4 acc[4][4];
#pragma unroll
  for (int i = 0; i < 4; ++i)
#pragma unroll
    for (int j = 0; j < 4; ++j) acc[i][j] = (f32x4){0.f, 0.f, 0.f, 0.f};
  bf16x8 af0[2][2], af1[2][2], bf0[2][2], bf1[2][2];

  // prologue: 2 K-tiles in flight (B then A per tile; 16 loads outstanding)
  STAGE_B(0, 0); STAGE_A(0, 0);
  STAGE_B(1, 1); STAGE_A(1, 1);

  // main loop: 12 K-tiles, stage kt+2, counted vmcnt(8)
  for (int kt = 0; kt < 10; kt += 2) {
    ITER(0, true, kt + 2, 8);
    ITER(1, true, kt + 3, 8);
  }
  ITER(0, false, 0, 8);   // kt=10: tile 11 still in flight
  ITER(1, false, 0, 0);   // kt=11: final drain

#undef ITER
#undef MFMAQ
#undef LDB
#undef LDA
#undef STAGE_B
#undef STAGE_A

  // epilogue: C write (bf16), wave tile 64x64 at (wr*64, wc*64)
#pragma unroll
  for (int i = 0; i < 4; ++i)
#pragma unroll
    for (int j = 0; j < 4; ++j)
#pragma unroll
      for (int r = 0; r < 4; ++r) {
        int row = m0 + wr * 64 + i * 16 + quad * 4 + r;
        int col = n0 + wc * 64 + j * 16 + l16;
        Cb[(size_t)row * 2304 + col] = cvt_bf16(acc[i][j][r]);
      }
}

// ---------------------------------------------------------------------------
// Pool + bias + LayerNorm, MFMA, BK=128 (2 hw per iter, 25 iters).
// Double-buffered staging with counted vmcnt(8) — R6-verified.
// ---------------------------------------------------------------------------
__global__ __launch_bounds__(256) void pool_ln_mfma_k(
    const unsigned short* __restrict__ qkvb, const unsigned short* __restrict__ WpTT,
    const float* __restrict__ bq, const float* __restrict__ bk, const float* __restrict__ bv,
    const float* __restrict__ gq, const float* __restrict__ gk, const float* __restrict__ gv,
    const float* __restrict__ beq, const float* __restrict__ bek, const float* __restrict__ bev,
    unsigned short* __restrict__ oq, unsigned short* __restrict__ ok_,
    unsigned short* __restrict__ ov) {
  __shared__ float smem_f[16384];          // 64 KB: A0,A1,B0,B1 bf16 / Ln alias
  __shared__ float mu_s[64], rs_s[64];
  unsigned short* AB = (unsigned short*)smem_f;  // A(buf)=AB+buf*8192; B=+16384
  float* Ln = smem_f;                      // [64][65], valid after K-loop

  const int n = blockIdx.x, p = blockIdx.y, b = blockIdx.z;
  const int tid = threadIdx.x;
  const int wave = tid >> 6, lane = tid & 63;
  const int quad = lane >> 4, l16 = lane & 15;
  const int wm = (wave >> 1) * 32, wn = (wave & 1) * 32;

  const int lr = lane >> 4, lg = lane & 15;
  const size_t abase = ((size_t)b * 3136) * 2304 + (size_t)p * 768 + (size_t)n * 64;
  const unsigned short* WpB = WpTT + (size_t)p * 204800;

  const unsigned short* pA[4];
  const unsigned short* pB[4];
#pragma unroll
  for (int q = 0; q < 4; ++q) {
    int r = wave * 16 + q * 4 + lr;
    int g = lg ^ (r & 15);
    pA[q] = qkvb + abase + (size_t)r * 112896 + (size_t)(g >> 3) * 2304 + (g & 7) * 8;
    pB[q] = WpB + (size_t)(g >> 3) * 4096 + r * 64 + (g & 7) * 8;
  }

#define PSTAGE(buf, it) do {                                                       \
    const size_t offA_ = (size_t)(it) * 4608;                                      \
    const size_t offB_ = (size_t)(it) * 8192;                                      \
    unsigned short* Ad_ = AB + (buf) * 8192;                                       \
    unsigned short* Bd_ = AB + 16384 + (buf) * 8192;                               \
    _Pragma("unroll")                                                              \
    for (int q_ = 0; q_ < 4; ++q_) {                                               \
      __builtin_amdgcn_global_load_lds(AS1U(pA[q_] + offA_),                       \
          AS3U(&Ad_[(wave * 16 + q_ * 4) * 128]), 16, 0, 0);                       \
      __builtin_amdgcn_global_load_lds(AS1U(pB[q_] + offB_),                       \
          AS3U(&Bd_[(wave * 16 + q_ * 4) * 128]), 16, 0, 0);                       \
    }                                                                              \
  } while (0)

#define PCOMPUTE(buf) do {                                                         \
    const unsigned short* Ad_ = AB + (buf) * 8192;                                 \
    const unsigned short* Bd_ = AB + 16384 + (buf) * 8192;                         \
    bf16x8 af_[2][4], bf_[2][4];                                                   \
    _Pragma("unroll")                                                              \
    for (int f_ = 0; f_ < 2; ++f_) {                                               \
      int ra_ = wm + f_ * 16 + l16;                                                \
      int rb_ = wn + f_ * 16 + l16;                                                \
      _Pragma("unroll")                                                            \
      for (int ki_ = 0; ki_ < 4; ++ki_) {                                          \
        af_[f_][ki_] = *(const bf16x8*)&Ad_[ra_ * 128 +                            \
            (((ki_ * 4 + quad) ^ (ra_ & 15)) * 8)];                                \
        bf_[f_][ki_] = *(const bf16x8*)&Bd_[rb_ * 128 +                            \
            (((ki_ * 4 + quad) ^ (rb_ & 15)) * 8)];                                \
      }                                                                            \
    }                                                                              \
    _Pragma("unroll")                                                              \
    for (int ki_ = 0; ki_ < 4; ++ki_)                                              \
      _Pragma("unroll")                                                            \
      for (int i_ = 0; i_ < 2; ++i_)                                               \
        _Pragma("unroll")                                                          \
        for (int j_ = 0; j_ < 2; ++j_)                                             \
          acc[i_][j_] = __builtin_amdgcn_mfma_f32_16x16x32_bf16(                   \
              af_[i_][ki_], bf_[j_][ki_], acc[i_][j_], 0, 0, 0);                   \
  } while (0)

  f32x4 acc[2][2];
#pragma unroll
  for (int i = 0; i < 2; ++i)
#pragma unroll
    for (int j = 0; j < 2; ++j) acc[i][j] = (f32x4){0.f, 0.f, 0.f, 0.f};

  PSTAGE(0, 0);
  for (int it2 = 0; it2 < 24; it2 += 2) {
    PSTAGE(1, it2 + 1);
    asm volatile("s_waitcnt vmcnt(8)" ::: "memory");
    wg_barrier();
    PCOMPUTE(0);
    wg_barrier();
    PSTAGE(0, it2 + 2);
    asm volatile("s_waitcnt vmcnt(8)" ::: "memory");
    wg_barrier();
    PCOMPUTE(1);
    wg_barrier();
  }
  // it = 24 (buf 0), last tile -> full drain
  asm volatile("s_waitcnt vmcnt(0)" ::: "memory");
  wg_barrier();
  PCOMPUTE(0);
  __syncthreads();                         // all reads done before Ln aliases AB

#undef PCOMPUTE
#undef PSTAGE

  const float* bias = (p == 0) ? bq : (p == 1) ? bk : bv;
  const float* g    = (p == 0) ? gq : (p == 1) ? gk : gv;
  const float* be   = (p == 0) ? beq : (p == 1) ? bek : bev;
  unsigned short* outp = (p == 0) ? oq : (p == 1) ? ok_ : ov;

#pragma unroll
  for (int i = 0; i < 2; ++i)
#pragma unroll
    for (int j = 0; j < 2; ++j)
#pragma unroll
      for (int r = 0; r < 4; ++r) {
        int t = wm + i * 16 + quad * 4 + r;
        int d = wn + j * 16 + l16;
        Ln[t * 65 + d] = acc[i][j][r] + bias[d];
      }
  __syncthreads();
  if (tid < 64) {
    float s = 0.f;
#pragma unroll 8
    for (int c = 0; c < 64; ++c) s += Ln[tid * 65 + c];
    float m = s * (1.f / 64.f);
    float v2 = 0.f;
#pragma unroll 8
    for (int c = 0; c < 64; ++c) { float dl = Ln[tid * 65 + c] - m; v2 += dl * dl; }
    mu_s[tid] = m;
    rs_s[tid] = rsqrtf(v2 * (1.f / 64.f) + 1e-5f);
  }
  __syncthreads();
  {
    int t = tid >> 2, d0 = (tid & 3) * 16;
    float m = mu_s[t], rv = rs_s[t];
    unsigned short ob[16];
#pragma unroll
    for (int j = 0; j < 16; ++j)
      ob[j] = cvt_bf16((Ln[t * 65 + d0 + j] - m) * rv * g[d0 + j] + be[d0 + j]);
    unsigned short* dst = outp + ((size_t)(b * 12 + n) * 64 + t) * 64 + d0;
    *(uint4*)dst = *(uint4*)ob;
    *(uint4*)(dst + 8) = *(uint4*)(ob + 8);
  }
}

// ---------------------------------------------------------------------------
// Fused MFMA attention per (b,n) — R3-verified verbatim.
// ---------------------------------------------------------------------------
__global__ __launch_bounds__(256) void attn_mfma_k(
    const unsigned short* __restrict__ qp, const unsigned short* __restrict__ kp,
    const unsigned short* __restrict__ vp, const unsigned short* __restrict__ relb,
    float* __restrict__ aout) {
  __shared__ unsigned short qs[64 * 64];
  __shared__ unsigned short ks[64 * 64];
  __shared__ unsigned short vt[64 * 64];
  __shared__ unsigned short rs[128 * 64];
  __shared__ float Gs[64 * 128];
  __shared__ unsigned short Ps[64 * 64];

  const int n = blockIdx.x, b = blockIdx.y;
  const int tid = threadIdx.x;
  const size_t base = ((size_t)b * 12 + n) * 4096;

  for (int i = tid; i < 512; i += 256) {
    ((uint4*)qs)[i] = ((const uint4*)(qp + base))[i];
    ((uint4*)ks)[i] = ((const uint4*)(kp + base))[i];
  }
  for (int i = tid; i < 1024; i += 256)
    ((uint4*)rs)[i] = ((const uint4*)relb)[i];
  {
    int s = tid >> 2, c0 = (tid & 3) * 16;
    unsigned short tmp[16];
    *(uint4*)tmp = *(const uint4*)(vp + base + s * 64 + c0);
    *(uint4*)(tmp + 8) = *(const uint4*)(vp + base + s * 64 + c0 + 8);
#pragma unroll
    for (int i = 0; i < 16; ++i) vt[(c0 + i) * 64 + s] = tmp[i];
  }
  __syncthreads();

  const int wave = tid >> 6, lane = tid & 63;
  const int quad = lane >> 4, l16 = lane & 15;
  const int tm = wave * 16;

  bf16x8 aq[2];
  aq[0] = *(const bf16x8*)&qs[(tm + l16) * 64 + quad * 8];
  aq[1] = *(const bf16x8*)&qs[(tm + l16) * 64 + quad * 8 + 32];

  f32x4 accqk[4], accg[8];
#pragma unroll
  for (int j = 0; j < 4; ++j) accqk[j] = (f32x4){0.f, 0.f, 0.f, 0.f};
#pragma unroll
  for (int j = 0; j < 8; ++j) accg[j] = (f32x4){0.f, 0.f, 0.f, 0.f};

#pragma unroll
  for (int ki = 0; ki < 2; ++ki) {
#pragma unroll
    for (int j = 0; j < 4; ++j) {
      bf16x8 bk = *(const bf16x8*)&ks[(j * 16 + l16) * 64 + quad * 8 + ki * 32];
      accqk[j] = __builtin_amdgcn_mfma_f32_16x16x32_bf16(aq[ki], bk, accqk[j], 0, 0, 0);
    }
#pragma unroll
    for (int j = 0; j < 8; ++j) {
      bf16x8 br = *(const bf16x8*)&rs[(j * 16 + l16) * 64 + quad * 8 + ki * 32];
      accg[j] = __builtin_amdgcn_mfma_f32_16x16x32_bf16(aq[ki], br, accg[j], 0, 0, 0);
    }
  }
#pragma unroll
  for (int j = 0; j < 8; ++j)
#pragma unroll
    for (int r = 0; r < 4; ++r)
      Gs[(tm + quad * 4 + r) * 128 + j * 16 + l16] = accg[j][r];
  __syncthreads();

#pragma unroll
  for (int r = 0; r < 4; ++r) {
    int t = tm + quad * 4 + r;
    float sv[4];
#pragma unroll
    for (int j = 0; j < 4; ++j) {
      int s = j * 16 + l16;
      sv[j] = 0.125f * accqk[j][r] + Gs[t * 128 + (t + 63 - s)];
    }
    float m = fmaxf(fmaxf(sv[0], sv[1]), fmaxf(sv[2], sv[3]));
    m = fmaxf(m, __shfl_xor(m, 1));
    m = fmaxf(m, __shfl_xor(m, 2));
    m = fmaxf(m, __shfl_xor(m, 4));
    m = fmaxf(m, __shfl_xor(m, 8));
    float e[4], sum = 0.f;
#pragma unroll
    for (int j = 0; j < 4; ++j) { e[j] = __expf(sv[j] - m); sum += e[j]; }
    sum += __shfl_xor(sum, 1);
    sum += __shfl_xor(sum, 2);
    sum += __shfl_xor(sum, 4);
    sum += __shfl_xor(sum, 8);
    float inv = 1.f / sum;
#pragma unroll
    for (int j = 0; j < 4; ++j)
      Ps[t * 64 + j * 16 + l16] = cvt_bf16(e[j] * inv);
  }
  __syncthreads();

  bf16x8 ap[2];
  ap[0] = *(const bf16x8*)&Ps[(tm + l16) * 64 + quad * 8];
  ap[1] = *(const bf16x8*)&Ps[(tm + l16) * 64 + quad * 8 + 32];
  f32x4 acco[4];
#pragma unroll
  for (int j = 0; j < 4; ++j) acco[j] = (f32x4){0.f, 0.f, 0.f, 0.f};
#pragma unroll
  for (int ki = 0; ki < 2; ++ki)
#pragma unroll
    for (int j = 0; j < 4; ++j) {
      bf16x8 bv = *(const bf16x8*)&vt[(j * 16 + l16) * 64 + quad * 8 + ki * 32];
      acco[j] = __builtin_amdgcn_mfma_f32_16x16x32_bf16(ap[ki], bv, acco[j], 0, 0, 0);
    }
#pragma unroll
  for (int j = 0; j < 4; ++j)
#pragma unroll
    for (int r = 0; r < 4; ++r) {
      int t = tm + quad * 4 + r;
      int c = j * 16 + l16;
      float o = acco[j][r] + bf2f(qs[t * 64 + c]);
      aout[((size_t)b * 64 + t) * 768 + n * 64 + c] = o;
    }
}

// ---------------------------------------------------------------------------
// fp32 GEMM (final projection): C[m,n] = sum_k A[m,k]*B[k,n] + bias[n]
// ---------------------------------------------------------------------------
__global__ __launch_bounds__(256) void gemm_f32_k(
    const float* __restrict__ A, const float* __restrict__ Bm,
    const float* __restrict__ bias, float* __restrict__ Cm,
    int M, int Nn, int K) {
  __shared__ float As[16][68];
  __shared__ float Bs[16][64];
  const int tid = threadIdx.x;
  const int ty = tid >> 4, tx = tid & 15;
  const int m0 = blockIdx.y * 64, n0 = blockIdx.x * 64;

  const int la_m = tid >> 2;
  const int la_k = (tid & 3) << 2;
  const int lb_k = tid >> 4;
  const int lb_n = (tid & 15) << 2;

  const float* Ap = A + (size_t)(m0 + la_m) * K + la_k;
  const float* Bp = Bm + (size_t)lb_k * Nn + n0 + lb_n;

  float acc[4][4];
#pragma unroll
  for (int i = 0; i < 4; ++i)
#pragma unroll
    for (int j = 0; j < 4; ++j) acc[i][j] = 0.f;

  for (int k0 = 0; k0 < K; k0 += 16) {
    float4 av = *(const float4*)(Ap + k0);
    float4 bv = *(const float4*)(Bp + (size_t)k0 * Nn);
    As[la_k + 0][la_m] = av.x;
    As[la_k + 1][la_m] = av.y;
    As[la_k + 2][la_m] = av.z;
    As[la_k + 3][la_m] = av.w;
    *(float4*)&Bs[lb_k][lb_n] = bv;
    __syncthreads();
#pragma unroll
    for (int kk = 0; kk < 16; ++kk) {
      float af[4], bf[4];
      *(float4*)af = *(const float4*)&As[kk][ty << 2];
      *(float4*)bf = *(const float4*)&Bs[kk][tx << 2];
#pragma unroll
      for (int i = 0; i < 4; ++i)
#pragma unroll
        for (int j = 0; j < 4; ++j) acc[i][j] += af[i] * bf[j];
    }
    __syncthreads();
  }

  float bb[4] = {0.f, 0.f, 0.f, 0.f};
  if (bias) {
#pragma unroll
    for (int j = 0; j < 4; ++j) bb[j] = bias[n0 + (tx << 2) + j];
  }
#pragma unroll
  for (int i = 0; i < 4; ++i) {
    float4 o;
    o.x = acc[i][0] + bb[0];
    o.y = acc[i][1] + bb[1];
    o.z = acc[i][2] + bb[2];
    o.w = acc[i][3] + bb[3];
    *(float4*)(Cm + (size_t)(m0 + (ty << 2) + i) * Nn + n0 + (tx << 2)) = o;
  }
}

// ---------------------------------------------------------------------------
extern "C" void kernel_launch(void* const* d_in, const int* in_sizes, int n_in,
                              void* d_out, int out_size, void* d_ws, size_t ws_size,
                              hipStream_t stream) {
  const float* x     = (const float*)d_in[0];
  const float* Wqkv  = (const float*)d_in[1];
  const float* Wpq   = (const float*)d_in[2];
  const float* bpq   = (const float*)d_in[3];
  const float* Wpk   = (const float*)d_in[4];
  const float* bpk   = (const float*)d_in[5];
  const float* Wpv   = (const float*)d_in[6];
  const float* bpv   = (const float*)d_in[7];
  const float* gq    = (const float*)d_in[8];
  const float* beq   = (const float*)d_in[9];
  const float* gk    = (const float*)d_in[10];
  const float* bek   = (const float*)d_in[11];
  const float* gv    = (const float*)d_in[12];
  const float* bev   = (const float*)d_in[13];
  const float* relp  = (const float*)d_in[14];
  const float* Wproj = (const float*)d_in[15];
  const float* bproj = (const float*)d_in[16];
  float* out = (float*)d_out;

  unsigned short* u = (unsigned short*)d_ws;
  unsigned short* xbf   = u;                       // 38,535,168 us
  unsigned short* qkvbf = u + 38535168ull;         // 115,605,504 us
  unsigned short* WqkvT = u + 154140672ull;        // 1,769,472 us
  unsigned short* WpTT  = u + 155910144ull;        // 614,400 us
  unsigned short* relb  = u + 156524544ull;        // 8,192 us
  unsigned short* qpb   = u + 156532736ull;        // 786,432 us
  unsigned short* kpb   = u + 157319168ull;        // 786,432 us
  unsigned short* vpb   = u + 158105600ull;        // 786,432 us
  float* aout = (float*)(u + 158892032ull);        // 786,432 f32

  cvt_x_k<<<18816, 256, 0, stream>>>(x, xbf, 4816896);
  transpose_cvt_k<<<dim3(24, 72), 256, 0, stream>>>(Wqkv, WqkvT);
  prep_cvt_k<<<2432, 256, 0, stream>>>(Wpq, Wpk, Wpv, relp, WpTT, relb);

  // qkv = x @ Wqkv (bf16 MFMA, 128x128 4-phase, 2 blocks/CU) — two nb-halves
  gemm_qkv_128<<<3528, 256, 0, stream>>>(xbf, WqkvT, qkvbf, 0);
  gemm_qkv_128<<<3528, 256, 0, stream>>>(xbf, WqkvT, qkvbf, 9);

  // pooling + bias + LN (bf16 MFMA, double-buffered)
  pool_ln_mfma_k<<<dim3(12, 3, 16), 256, 0, stream>>>(
      qkvbf, WpTT, bpq, bpk, bpv, gq, gk, gv, beq, bek, bev, qpb, kpb, vpb);

  // attention (MFMA)
  attn_mfma_k<<<dim3(12, 16), 256, 0, stream>>>(qpb, kpb, vpb, relb, aout);

  // final projection (fp32)
  gemm_f32_k<<<dim3(12, 16), 256, 0, stream>>>(aout, Wproj, bproj, out, 1024, 768, 768);
}